// Round 5
// baseline (464.892 us; speedup 1.0000x reference)
//
#include <hip/hip_runtime.h>

#define D 128
#define KTOT 256
#define GM 128
#define LPAD 8
#define LSTR (KTOT + LPAD)   // 264
#define NPASS 4
#define HBINS 26000
#define NHB 32

typedef __attribute__((ext_vector_type(8))) short bf16x8;
typedef __attribute__((ext_vector_type(4))) float f32x4;

__device__ __forceinline__ unsigned short f2b(float f) {
    unsigned int u = __float_as_uint(f);
    u += 0x7fffu + ((u >> 16) & 1u);   // RNE (inputs are finite)
    return (unsigned short)(u >> 16);
}
__device__ __forceinline__ float blo(unsigned int u) { return __uint_as_float(u << 16); }
__device__ __forceinline__ float bhi(unsigned int u) { return __uint_as_float(u & 0xffff0000u); }

// ---------------------------------------------------------------------------
// Probe: int64 vs int32 edge_index layout
// ---------------------------------------------------------------------------
__global__ void detect_kernel(const unsigned int* __restrict__ ei, int* __restrict__ flag) {
    int all0 = 1;
    for (int i = 0; i < 128; ++i) {
        if (ei[2 * i + 1] != 0u) { all0 = 0; break; }
    }
    *flag = all0;
}

// ---------------------------------------------------------------------------
// Pure pack: edge list -> int32 arrays (no atomics)
// ---------------------------------------------------------------------------
__global__ __launch_bounds__(256) void pack_kernel(
    const void* __restrict__ ei, const int* __restrict__ flag,
    int* __restrict__ src32, int* __restrict__ dst32, int n_edges)
{
    int e = blockIdx.x * 256 + threadIdx.x;
    if (e >= n_edges) return;
    int s, d;
    if (*flag) {
        const long long* p = (const long long*)ei;
        s = (int)p[e]; d = (int)p[n_edges + e];
    } else {
        const int* p = (const int*)ei;
        s = p[e]; d = p[n_edges + e];
    }
    src32[e] = s;
    dst32[e] = d;
}

// ---------------------------------------------------------------------------
// LDS-privatized multipass histogram. NHB blocks; pass p covers bins
// [p*HBINS,(p+1)*HBINS). Partials -> scratch [pass][block][HBINS]. No global
// atomics; fully deterministic.
// ---------------------------------------------------------------------------
__global__ __launch_bounds__(256) void hist_kernel(
    const int* __restrict__ dst32, int n_edges, int n_nodes,
    int* __restrict__ partials)
{
    __shared__ int h[HBINS];
    const int hp = (n_nodes + HBINS - 1) / HBINS;
    for (int p = 0; p < hp; ++p) {
        const int lo = p * HBINS;
        const int bins = min(HBINS, n_nodes - lo);
        for (int i = threadIdx.x; i < bins; i += 256) h[i] = 0;
        __syncthreads();
        for (int e = blockIdx.x * 256 + threadIdx.x; e < n_edges; e += gridDim.x * 256) {
            int d = dst32[e] - lo;
            if (d >= 0 && d < bins) atomicAdd(&h[d], 1);   // LDS atomic
        }
        __syncthreads();
        int* out = partials + ((long long)p * gridDim.x + blockIdx.x) * HBINS;
        for (int i = threadIdx.x; i < bins; i += 256) out[i] = h[i];
        __syncthreads();
    }
}

// ---------------------------------------------------------------------------
// Scan stage 1 fused with partial reduction: deg[i] = sum_b partials[p][b][bin]
// -> block-exclusive scan into row_start; block totals to blockSums.
// ---------------------------------------------------------------------------
__global__ __launch_bounds__(1024) void scan1_kernel(
    const int* __restrict__ partials, int nhb,
    int* __restrict__ row_start, int* __restrict__ blockSums, int n)
{
    __shared__ int sm[1024];
    const int tid = threadIdx.x;
    const int i = blockIdx.x * 1024 + tid;
    int v = 0;
    if (i < n) {
        const int p = i / HBINS, bin = i - p * HBINS;
        const int* base = partials + ((long long)p * nhb) * HBINS + bin;
        #pragma unroll 8
        for (int b = 0; b < nhb; ++b) v += base[(long long)b * HBINS];
    }
    int val = v;
    sm[tid] = val;
    __syncthreads();
    for (int off = 1; off < 1024; off <<= 1) {
        int t = (tid >= off) ? sm[tid - off] : 0;
        __syncthreads();
        val += t;
        sm[tid] = val;
        __syncthreads();
    }
    if (i < n) row_start[i] = val - v;
    if (tid == 1023) blockSums[blockIdx.x] = val;
}

__global__ __launch_bounds__(128) void scan2_kernel(int* __restrict__ bs, int nb)
{
    __shared__ int sm[128];
    int t = threadIdx.x;
    int v = (t < nb) ? bs[t] : 0;
    int val = v;
    sm[t] = val;
    __syncthreads();
    for (int off = 1; off < 128; off <<= 1) {
        int u = (t >= off) ? sm[t - off] : 0;
        __syncthreads();
        val += u;
        sm[t] = val;
        __syncthreads();
    }
    if (t < nb) bs[t] = val - v;
}

__global__ __launch_bounds__(1024) void scan3_kernel(
    int* __restrict__ row_start, const int* __restrict__ blockSums, int n)
{
    const int i = blockIdx.x * 1024 + threadIdx.x;
    if (i >= n) return;
    row_start[i] += blockSums[blockIdx.x];
}

// ---------------------------------------------------------------------------
// Range-partitioned CSR fill (mutates row_start into row_end over passes)
// ---------------------------------------------------------------------------
__global__ __launch_bounds__(256) void fill_pass_kernel(
    const int* __restrict__ src32, const int* __restrict__ dst32,
    int* __restrict__ row_start, int* __restrict__ sorted_src,
    int n_edges, int lo, int hi)
{
    int e = blockIdx.x * 256 + threadIdx.x;
    if (e >= n_edges) return;
    int d = dst32[e];
    if (d >= lo && d < hi) {
        int pos = atomicAdd(&row_start[d], 1);
        sorted_src[pos] = src32[e];
    }
}

// ---------------------------------------------------------------------------
// f32 -> bf16 bulk convert
// ---------------------------------------------------------------------------
__global__ __launch_bounds__(256) void cvt_kernel(
    const float* __restrict__ in, unsigned short* __restrict__ out, long long nelem)
{
    long long i = ((long long)blockIdx.x * 256 + threadIdx.x) * 8;
    if (i >= nelem) return;
    float4 a = *(const float4*)(in + i);
    float4 b = *(const float4*)(in + i + 4);
    bf16x8 v;
    v[0] = (short)f2b(a.x); v[1] = (short)f2b(a.y);
    v[2] = (short)f2b(a.z); v[3] = (short)f2b(a.w);
    v[4] = (short)f2b(b.x); v[5] = (short)f2b(b.y);
    v[6] = (short)f2b(b.z); v[7] = (short)f2b(b.w);
    *(bf16x8*)(out + i) = v;
}

// Wt[c][k] = (k<128 ? Wr[k][c] : Wl[k-128][c]) as bf16  — [128][256]
__global__ __launch_bounds__(256) void wt_kernel(
    const float* __restrict__ Wr, const float* __restrict__ Wl,
    unsigned short* __restrict__ Wt)
{
    int c = blockIdx.x, k = threadIdx.x;
    float v = (k < 128) ? Wr[k * D + c] : Wl[(k - 128) * D + c];
    Wt[c * KTOT + k] = f2b(v);
}

// ---------------------------------------------------------------------------
// CSR gather aggregation: wave per node, 16 lanes x uint4, 4 edges/iter x2
// ---------------------------------------------------------------------------
__global__ __launch_bounds__(256) void agg_kernel(
    const unsigned short* __restrict__ src, const int* __restrict__ sorted_src,
    const int* __restrict__ row_end, unsigned short* __restrict__ dst, int n)
{
    const int node = blockIdx.x * 4 + (threadIdx.x >> 6);
    if (node >= n) return;
    const int lane = threadIdx.x & 63;
    const int j = lane >> 4;
    const int c = (lane & 15) * 8;
    const int beg = node ? row_end[node - 1] : 0;
    const int end = row_end[node];

    float a0 = 0.f, a1 = 0.f, a2 = 0.f, a3 = 0.f,
          a4 = 0.f, a5 = 0.f, a6 = 0.f, a7 = 0.f;

    int i = beg + j;
    for (; i + 4 < end; i += 8) {
        int s0 = sorted_src[i];
        int s1 = sorted_src[i + 4];
        uint4 u0 = *(const uint4*)(src + (long long)s0 * D + c);
        uint4 u1 = *(const uint4*)(src + (long long)s1 * D + c);
        a0 += blo(u0.x); a1 += bhi(u0.x); a2 += blo(u0.y); a3 += bhi(u0.y);
        a4 += blo(u0.z); a5 += bhi(u0.z); a6 += blo(u0.w); a7 += bhi(u0.w);
        a0 += blo(u1.x); a1 += bhi(u1.x); a2 += blo(u1.y); a3 += bhi(u1.y);
        a4 += blo(u1.z); a5 += bhi(u1.z); a6 += blo(u1.w); a7 += bhi(u1.w);
    }
    if (i < end) {
        int s0 = sorted_src[i];
        uint4 u0 = *(const uint4*)(src + (long long)s0 * D + c);
        a0 += blo(u0.x); a1 += bhi(u0.x); a2 += blo(u0.y); a3 += bhi(u0.y);
        a4 += blo(u0.z); a5 += bhi(u0.z); a6 += blo(u0.w); a7 += bhi(u0.w);
    }

    a0 += __shfl_xor(a0, 16); a1 += __shfl_xor(a1, 16);
    a2 += __shfl_xor(a2, 16); a3 += __shfl_xor(a3, 16);
    a4 += __shfl_xor(a4, 16); a5 += __shfl_xor(a5, 16);
    a6 += __shfl_xor(a6, 16); a7 += __shfl_xor(a7, 16);
    a0 += __shfl_xor(a0, 32); a1 += __shfl_xor(a1, 32);
    a2 += __shfl_xor(a2, 32); a3 += __shfl_xor(a3, 32);
    a4 += __shfl_xor(a4, 32); a5 += __shfl_xor(a5, 32);
    a6 += __shfl_xor(a6, 32); a7 += __shfl_xor(a7, 32);

    if (j == 0) {
        uint4 p;
        p.x = (unsigned int)f2b(a0) | ((unsigned int)f2b(a1) << 16);
        p.y = (unsigned int)f2b(a2) | ((unsigned int)f2b(a3) << 16);
        p.z = (unsigned int)f2b(a4) | ((unsigned int)f2b(a5) << 16);
        p.w = (unsigned int)f2b(a6) | ((unsigned int)f2b(a7) << 16);
        *(uint4*)(dst + (long long)node * D + c) = p;
    }
}

// ---------------------------------------------------------------------------
// MFMA GEMM: out = relu([X|A] @ Wt^T + b). A-fragments read DIRECTLY from
// global (each row consumed by exactly one wave -> LDS staging had no reuse).
// Only Wt is LDS-staged (67.6 KB -> 2 blocks/CU).
// ---------------------------------------------------------------------------
template <int OUT_BF16>
__global__ __launch_bounds__(512) void gemm_kernel(
    const unsigned short* __restrict__ Xop, const unsigned short* __restrict__ Aop,
    const unsigned short* __restrict__ Wt, const float* __restrict__ bias,
    void* __restrict__ outp, int n)
{
    __shared__ short sW[D][LSTR];
    const int tid = threadIdx.x;
    const int r0 = blockIdx.x * GM;

    for (int i = 0; i < 8; ++i) {
        int idx = tid + i * 512;
        int r = idx >> 5, c8 = idx & 31;
        bf16x8 w = *(const bf16x8*)(Wt + r * KTOT + c8 * 8);
        *(bf16x8*)&sW[r][c8 * 8] = w;
    }
    __syncthreads();

    const int w    = tid >> 6;
    const int lane = tid & 63;
    const int lr   = lane & 15;
    const int lk   = (lane >> 4) * 8;
    const int row  = r0 + w * 16 + lr;
    const bool rok = (row < n);

    f32x4 acc[8];
    #pragma unroll
    for (int ct = 0; ct < 8; ++ct) acc[ct] = (f32x4){0.f, 0.f, 0.f, 0.f};

    #pragma unroll
    for (int ks = 0; ks < 8; ++ks) {
        bf16x8 a = {};
        if (rok) {
            const unsigned short* base = (ks < 4) ? Xop : Aop;
            a = *(const bf16x8*)(base + (long long)row * D + (ks & 3) * 32 + lk);
        }
        #pragma unroll
        for (int ct = 0; ct < 8; ++ct) {
            bf16x8 bf = *(const bf16x8*)&sW[ct * 16 + lr][ks * 32 + lk];
            acc[ct] = __builtin_amdgcn_mfma_f32_16x16x32_bf16(a, bf, acc[ct], 0, 0, 0);
        }
    }

    // C/D: col = lane&15, row = (lane>>4)*4 + j
    const int rbase = r0 + w * 16 + (lane >> 4) * 4;
    #pragma unroll
    for (int ct = 0; ct < 8; ++ct) {
        const int col = ct * 16 + lr;
        const float bv = bias[col];
        #pragma unroll
        for (int j = 0; j < 4; ++j) {
            int orow = rbase + j;
            if (orow < n) {
                float val = fmaxf(acc[ct][j] + bv, 0.f);
                if (OUT_BF16) {
                    ((unsigned short*)outp)[(long long)orow * D + col] = f2b(val);
                } else {
                    ((float*)outp)[(long long)orow * D + col] = val;
                }
            }
        }
    }
}

static inline size_t align_up(size_t v, size_t a) { return (v + a - 1) & ~(a - 1); }

extern "C" void kernel_launch(void* const* d_in, const int* in_sizes, int n_in,
                              void* d_out, int out_size, void* d_ws, size_t ws_size,
                              hipStream_t stream) {
    const float* x   = (const float*)d_in[0];
    const void*  ei  = d_in[1];
    const float* Wr1 = (const float*)d_in[2];
    const float* Wl1 = (const float*)d_in[3];
    const float* b1  = (const float*)d_in[4];
    const float* Wr2 = (const float*)d_in[5];
    const float* Wl2 = (const float*)d_in[6];
    const float* b2  = (const float*)d_in[7];
    float* out = (float*)d_out;

    const int n_nodes = in_sizes[0] / D;
    const int n_edges = in_sizes[1] / 2;

    // ws layout (58.07 MB; proven available rounds 2-4)
    char* ws = (char*)d_ws;
    size_t off_flag = 0;
    size_t off_rs   = 256;
    size_t off_bs   = align_up(off_rs + 4 * (size_t)(n_nodes + 1), 256);
    size_t off_ssrc = align_up(off_bs + 4 * 1024, 256);
    size_t off_wt   = align_up(off_ssrc + 4 * (size_t)n_edges, 256);
    size_t off_xb   = align_up(off_wt + 2 * (size_t)D * KTOT, 256);
    size_t off_ab   = align_up(off_xb + 2 * (size_t)n_nodes * D, 256);

    int* flag            = (int*)(ws + off_flag);
    int* row_start       = (int*)(ws + off_rs);
    int* blockSums       = (int*)(ws + off_bs);
    int* sorted_src      = (int*)(ws + off_ssrc);
    unsigned short* Wt   = (unsigned short*)(ws + off_wt);
    unsigned short* Xb   = (unsigned short*)(ws + off_xb);
    unsigned short* Ab   = (unsigned short*)(ws + off_ab);
    // src32/dst32 alias Xb (dead until cvt); hist partials alias Ab (dead until agg)
    int* src32    = (int*)(ws + off_xb);
    int* dst32    = src32 + n_edges;
    int* partials = (int*)(ws + off_ab);   // [hp][NHB][HBINS] = 13.3 MB < 25.6 MB

    const int edge_blocks = (n_edges + 255) / 256;
    const int gemm_blocks = (n_nodes + GM - 1) / GM;
    const int agg_blocks  = (n_nodes + 3) / 4;
    const int nb          = (n_nodes + 1023) / 1024;
    const long long nfeat = (long long)n_nodes * D;

    detect_kernel<<<1, 1, 0, stream>>>((const unsigned int*)ei, flag);

    // ---- CSR build (once; no global atomics except fill cursors) ----
    pack_kernel<<<edge_blocks, 256, 0, stream>>>(ei, flag, src32, dst32, n_edges);
    hist_kernel<<<NHB, 256, 0, stream>>>(dst32, n_edges, n_nodes, partials);
    scan1_kernel<<<nb, 1024, 0, stream>>>(partials, NHB, row_start, blockSums, n_nodes);
    scan2_kernel<<<1, 128, 0, stream>>>(blockSums, nb);
    scan3_kernel<<<nb, 1024, 0, stream>>>(row_start, blockSums, n_nodes);
    const int rng = (n_nodes + NPASS - 1) / NPASS;
    for (int p = 0; p < NPASS; ++p) {
        fill_pass_kernel<<<edge_blocks, 256, 0, stream>>>(
            src32, dst32, row_start, sorted_src, n_edges, p * rng, (p + 1) * rng);
    }
    // row_start now holds row_end

    // ---- casts (cvt overwrites src32/dst32 — dead now) ----
    cvt_kernel<<<(int)((nfeat / 8 + 255) / 256), 256, 0, stream>>>(x, Xb, nfeat);
    wt_kernel<<<D, KTOT, 0, stream>>>(Wr1, Wl1, Wt);

    // ---- layer 1 (agg overwrites partials region — dead now) ----
    agg_kernel<<<agg_blocks, 256, 0, stream>>>(Xb, sorted_src, row_start, Ab, n_nodes);
    gemm_kernel<1><<<gemm_blocks, 512, 0, stream>>>(Xb, Ab, Wt, b1, Ab, n_nodes);

    // ---- layer 2 ----
    wt_kernel<<<D, KTOT, 0, stream>>>(Wr2, Wl2, Wt);
    agg_kernel<<<agg_blocks, 256, 0, stream>>>(Ab, sorted_src, row_start, Xb, n_nodes);
    gemm_kernel<0><<<gemm_blocks, 512, 0, stream>>>(Ab, Xb, Wt, b2, out, n_nodes);
}

// Round 6
// 269.615 us; speedup vs baseline: 1.7243x; 1.7243x over previous
//
#include <hip/hip_runtime.h>

#define D 128
#define KTOT 256
#define GM 128
#define LPAD 8
#define LSTR (KTOT + LPAD)   // 264

#define EB1   4096    // edges per pass-1 block
#define BKT_W 64      // nodes per coarse bucket
#define WIN   512     // buckets per scatter window (LDS cursor array)
#define EMAX  8192    // max edges per bucket handled in LDS (mean 1024, ~224 sigma margin)
#define HB1MAX 2048   // max coarse buckets (supports n_nodes <= 131072)

typedef __attribute__((ext_vector_type(8))) short bf16x8;
typedef __attribute__((ext_vector_type(4))) float f32x4;

__device__ __forceinline__ unsigned short f2b(float f) {
    unsigned int u = __float_as_uint(f);
    u += 0x7fffu + ((u >> 16) & 1u);   // RNE (inputs are finite)
    return (unsigned short)(u >> 16);
}
__device__ __forceinline__ float blo(unsigned int u) { return __uint_as_float(u << 16); }
__device__ __forceinline__ float bhi(unsigned int u) { return __uint_as_float(u & 0xffff0000u); }

// ---------------------------------------------------------------------------
// Probe: int64 vs int32 edge_index layout
// ---------------------------------------------------------------------------
__global__ void detect_kernel(const unsigned int* __restrict__ ei, int* __restrict__ flag) {
    int all0 = 1;
    for (int i = 0; i < 128; ++i) {
        if (ei[2 * i + 1] != 0u) { all0 = 0; break; }
    }
    *flag = all0;
}

// ---------------------------------------------------------------------------
// Pack: pk = (src<<6)|(dst&63), bkt = dst>>6. No atomics.
// ---------------------------------------------------------------------------
__global__ __launch_bounds__(256) void pack2_kernel(
    const void* __restrict__ ei, const int* __restrict__ flag,
    unsigned int* __restrict__ pk, unsigned short* __restrict__ bkt, int n_edges)
{
    int e = blockIdx.x * 256 + threadIdx.x;
    if (e >= n_edges) return;
    int s, d;
    if (*flag) {
        const long long* p = (const long long*)ei;
        s = (int)p[e]; d = (int)p[n_edges + e];
    } else {
        const int* p = (const int*)ei;
        s = p[e]; d = p[n_edges + e];
    }
    pk[e]  = ((unsigned int)s << 6) | (unsigned int)(d & (BKT_W - 1));
    bkt[e] = (unsigned short)(d >> 6);
}

// ---------------------------------------------------------------------------
// Pass-1 count: per-block LDS histogram over coarse buckets; contiguous write
// of C[blk][bucket]. LDS atomics only.
// ---------------------------------------------------------------------------
__global__ __launch_bounds__(256) void s1_count_kernel(
    const unsigned short* __restrict__ bkt, int n_edges, int nb1,
    int* __restrict__ C)
{
    __shared__ int h[HB1MAX];
    for (int i = threadIdx.x; i < nb1; i += 256) h[i] = 0;
    __syncthreads();
    const int e0 = blockIdx.x * EB1;
    const int e1 = min(e0 + EB1, n_edges);
    for (int e = e0 + threadIdx.x; e < e1; e += 256)
        atomicAdd(&h[bkt[e]], 1);
    __syncthreads();
    int* out = C + (long long)blockIdx.x * nb1;
    for (int i = threadIdx.x; i < nb1; i += 256) out[i] = h[i];
}

// ---------------------------------------------------------------------------
// Flat exclusive scan of C in bucket-major order (gather-transpose):
// Cs[b*nblk1 + k] = # edges in (bucket,block) pairs before (b,k).
// ---------------------------------------------------------------------------
__global__ __launch_bounds__(1024) void scanA_kernel(
    const int* __restrict__ C, int* __restrict__ Cs,
    int* __restrict__ blockSums, int L, int nb1, int nblk1)
{
    __shared__ int sm[1024];
    const int tid = threadIdx.x;
    const int i = blockIdx.x * 1024 + tid;
    int v = 0;
    if (i < L) {
        int b = i / nblk1, k = i - b * nblk1;
        v = C[(long long)k * nb1 + b];
    }
    int val = v;
    sm[tid] = val;
    __syncthreads();
    for (int off = 1; off < 1024; off <<= 1) {
        int t = (tid >= off) ? sm[tid - off] : 0;
        __syncthreads();
        val += t;
        sm[tid] = val;
        __syncthreads();
    }
    if (i < L) Cs[i] = val - v;
    if (tid == 1023) blockSums[blockIdx.x] = val;
}

__global__ __launch_bounds__(1024) void scan2_kernel(int* __restrict__ bs, int nb)
{
    __shared__ int sm[1024];
    int t = threadIdx.x;
    int v = (t < nb) ? bs[t] : 0;
    int val = v;
    sm[t] = val;
    __syncthreads();
    for (int off = 1; off < 1024; off <<= 1) {
        int u = (t >= off) ? sm[t - off] : 0;
        __syncthreads();
        val += u;
        sm[t] = val;
        __syncthreads();
    }
    if (t < nb) bs[t] = val - v;
}

__global__ __launch_bounds__(1024) void scan3_kernel(
    int* __restrict__ arr, const int* __restrict__ blockSums, int n)
{
    const int i = blockIdx.x * 1024 + threadIdx.x;
    if (i >= n) return;
    arr[i] += blockSums[blockIdx.x];
}

// ---------------------------------------------------------------------------
// Pass-1 scatter (windowed): group edges by coarse bucket. Cursors in LDS,
// seeded from Cs -> zero global atomics. Writes confined to ~2 MB window.
// ---------------------------------------------------------------------------
__global__ __launch_bounds__(256) void s1_scatter_kernel(
    const unsigned short* __restrict__ bkt, const unsigned int* __restrict__ pk,
    const int* __restrict__ Cs, unsigned int* __restrict__ sorted,
    int n_edges, int nb1, int nblk1, int lo)
{
    __shared__ int cur[WIN];
    const int hi = min(lo + WIN, nb1);
    for (int t = threadIdx.x; t < hi - lo; t += 256)
        cur[t] = Cs[(long long)(lo + t) * nblk1 + blockIdx.x];
    __syncthreads();
    const int e0 = blockIdx.x * EB1;
    const int e1 = min(e0 + EB1, n_edges);
    for (int e = e0 + threadIdx.x; e < e1; e += 256) {
        int b = bkt[e];
        if (b >= lo && b < hi) {
            int pos = atomicAdd(&cur[b - lo], 1);   // LDS atomic
            sorted[pos] = pk[e];
        }
    }
}

// ---------------------------------------------------------------------------
// Pass-2: one block per coarse bucket. LDS 64-bin counting sort by exact dst,
// writes row_end[node] and rewrites sorted[] (pk -> src) in place.
// ---------------------------------------------------------------------------
__global__ __launch_bounds__(256) void bucket_sort_kernel(
    unsigned int* __restrict__ sorted, const int* __restrict__ Cs,
    int n_edges, int n_nodes, int nb1, int nblk1, int* __restrict__ row_end)
{
    __shared__ unsigned int lpk[EMAX];
    __shared__ int h64[BKT_W], excl[BKT_W + 1], cur[BKT_W];
    const int b = blockIdx.x;
    const int t = threadIdx.x;
    const int base = Cs[(long long)b * nblk1];
    const int nextb = (b + 1 < nb1) ? Cs[(long long)(b + 1) * nblk1] : n_edges;
    const int cnt = min(nextb - base, EMAX);

    if (t < BKT_W) h64[t] = 0;
    for (int i = t; i < cnt; i += 256) lpk[i] = sorted[base + i];
    __syncthreads();
    for (int i = t; i < cnt; i += 256) atomicAdd(&h64[lpk[i] & (BKT_W - 1)], 1);
    __syncthreads();
    if (t == 0) {
        int run = 0;
        #pragma unroll
        for (int i = 0; i < BKT_W; ++i) { excl[i] = run; run += h64[i]; }
        excl[BKT_W] = run;
    }
    __syncthreads();
    const int node0 = b * BKT_W;
    const int bins = min(BKT_W, n_nodes - node0);
    if (t < bins) row_end[node0 + t] = base + excl[t + 1];
    if (t < BKT_W) cur[t] = excl[t];
    __syncthreads();
    for (int i = t; i < cnt; i += 256) {
        unsigned int p = lpk[i];
        int pos = atomicAdd(&cur[p & (BKT_W - 1)], 1);   // LDS atomic
        sorted[base + pos] = p >> 6;                     // src
    }
}

// ---------------------------------------------------------------------------
// f32 -> bf16 bulk convert
// ---------------------------------------------------------------------------
__global__ __launch_bounds__(256) void cvt_kernel(
    const float* __restrict__ in, unsigned short* __restrict__ out, long long nelem)
{
    long long i = ((long long)blockIdx.x * 256 + threadIdx.x) * 8;
    if (i >= nelem) return;
    float4 a = *(const float4*)(in + i);
    float4 b = *(const float4*)(in + i + 4);
    bf16x8 v;
    v[0] = (short)f2b(a.x); v[1] = (short)f2b(a.y);
    v[2] = (short)f2b(a.z); v[3] = (short)f2b(a.w);
    v[4] = (short)f2b(b.x); v[5] = (short)f2b(b.y);
    v[6] = (short)f2b(b.z); v[7] = (short)f2b(b.w);
    *(bf16x8*)(out + i) = v;
}

// Wt[c][k] = (k<128 ? Wr[k][c] : Wl[k-128][c]) as bf16  — [128][256]
__global__ __launch_bounds__(256) void wt_kernel(
    const float* __restrict__ Wr, const float* __restrict__ Wl,
    unsigned short* __restrict__ Wt)
{
    int c = blockIdx.x, k = threadIdx.x;
    float v = (k < 128) ? Wr[k * D + c] : Wl[(k - 128) * D + c];
    Wt[c * KTOT + k] = f2b(v);
}

// ---------------------------------------------------------------------------
// CSR gather aggregation: wave per node, 16 lanes x uint4, 4 edges/iter x2
// ---------------------------------------------------------------------------
__global__ __launch_bounds__(256) void agg_kernel(
    const unsigned short* __restrict__ src, const int* __restrict__ sorted_src,
    const int* __restrict__ row_end, unsigned short* __restrict__ dst, int n)
{
    const int node = blockIdx.x * 4 + (threadIdx.x >> 6);
    if (node >= n) return;
    const int lane = threadIdx.x & 63;
    const int j = lane >> 4;
    const int c = (lane & 15) * 8;
    const int beg = node ? row_end[node - 1] : 0;
    const int end = row_end[node];

    float a0 = 0.f, a1 = 0.f, a2 = 0.f, a3 = 0.f,
          a4 = 0.f, a5 = 0.f, a6 = 0.f, a7 = 0.f;

    int i = beg + j;
    for (; i + 4 < end; i += 8) {
        int s0 = sorted_src[i];
        int s1 = sorted_src[i + 4];
        uint4 u0 = *(const uint4*)(src + (long long)s0 * D + c);
        uint4 u1 = *(const uint4*)(src + (long long)s1 * D + c);
        a0 += blo(u0.x); a1 += bhi(u0.x); a2 += blo(u0.y); a3 += bhi(u0.y);
        a4 += blo(u0.z); a5 += bhi(u0.z); a6 += blo(u0.w); a7 += bhi(u0.w);
        a0 += blo(u1.x); a1 += bhi(u1.x); a2 += blo(u1.y); a3 += bhi(u1.y);
        a4 += blo(u1.z); a5 += bhi(u1.z); a6 += blo(u1.w); a7 += bhi(u1.w);
    }
    if (i < end) {
        int s0 = sorted_src[i];
        uint4 u0 = *(const uint4*)(src + (long long)s0 * D + c);
        a0 += blo(u0.x); a1 += bhi(u0.x); a2 += blo(u0.y); a3 += bhi(u0.y);
        a4 += blo(u0.z); a5 += bhi(u0.z); a6 += blo(u0.w); a7 += bhi(u0.w);
    }

    a0 += __shfl_xor(a0, 16); a1 += __shfl_xor(a1, 16);
    a2 += __shfl_xor(a2, 16); a3 += __shfl_xor(a3, 16);
    a4 += __shfl_xor(a4, 16); a5 += __shfl_xor(a5, 16);
    a6 += __shfl_xor(a6, 16); a7 += __shfl_xor(a7, 16);
    a0 += __shfl_xor(a0, 32); a1 += __shfl_xor(a1, 32);
    a2 += __shfl_xor(a2, 32); a3 += __shfl_xor(a3, 32);
    a4 += __shfl_xor(a4, 32); a5 += __shfl_xor(a5, 32);
    a6 += __shfl_xor(a6, 32); a7 += __shfl_xor(a7, 32);

    if (j == 0) {
        uint4 p;
        p.x = (unsigned int)f2b(a0) | ((unsigned int)f2b(a1) << 16);
        p.y = (unsigned int)f2b(a2) | ((unsigned int)f2b(a3) << 16);
        p.z = (unsigned int)f2b(a4) | ((unsigned int)f2b(a5) << 16);
        p.w = (unsigned int)f2b(a6) | ((unsigned int)f2b(a7) << 16);
        *(uint4*)(dst + (long long)node * D + c) = p;
    }
}

// ---------------------------------------------------------------------------
// MFMA GEMM: out = relu([X|A] @ Wt^T + b). A-fragments direct from global
// (one consumer wave per row -> LDS staging has no reuse). Wt LDS-staged.
// outp may alias Aop (waves read only their own 16-row span before writing).
// ---------------------------------------------------------------------------
template <int OUT_BF16>
__global__ __launch_bounds__(512) void gemm_kernel(
    const unsigned short* __restrict__ Xop, const unsigned short* __restrict__ Aop,
    const unsigned short* __restrict__ Wt, const float* __restrict__ bias,
    void* outp, int n)
{
    __shared__ short sW[D][LSTR];
    const int tid = threadIdx.x;
    const int r0 = blockIdx.x * GM;

    for (int i = 0; i < 8; ++i) {
        int idx = tid + i * 512;
        int r = idx >> 5, c8 = idx & 31;
        bf16x8 w = *(const bf16x8*)(Wt + r * KTOT + c8 * 8);
        *(bf16x8*)&sW[r][c8 * 8] = w;
    }
    __syncthreads();

    const int w    = tid >> 6;
    const int lane = tid & 63;
    const int lr   = lane & 15;
    const int lk   = (lane >> 4) * 8;
    const int row  = r0 + w * 16 + lr;
    const bool rok = (row < n);

    f32x4 acc[8];
    #pragma unroll
    for (int ct = 0; ct < 8; ++ct) acc[ct] = (f32x4){0.f, 0.f, 0.f, 0.f};

    #pragma unroll
    for (int ks = 0; ks < 8; ++ks) {
        bf16x8 a = {};
        if (rok) {
            const unsigned short* base = (ks < 4) ? Xop : Aop;
            a = *(const bf16x8*)(base + (long long)row * D + (ks & 3) * 32 + lk);
        }
        #pragma unroll
        for (int ct = 0; ct < 8; ++ct) {
            bf16x8 bf = *(const bf16x8*)&sW[ct * 16 + lr][ks * 32 + lk];
            acc[ct] = __builtin_amdgcn_mfma_f32_16x16x32_bf16(a, bf, acc[ct], 0, 0, 0);
        }
    }

    // C/D: col = lane&15, row = (lane>>4)*4 + j
    const int rbase = r0 + w * 16 + (lane >> 4) * 4;
    #pragma unroll
    for (int ct = 0; ct < 8; ++ct) {
        const int col = ct * 16 + lr;
        const float bv = bias[col];
        #pragma unroll
        for (int j = 0; j < 4; ++j) {
            int orow = rbase + j;
            if (orow < n) {
                float val = fmaxf(acc[ct][j] + bv, 0.f);
                if (OUT_BF16) {
                    ((unsigned short*)outp)[(long long)orow * D + col] = f2b(val);
                } else {
                    ((float*)outp)[(long long)orow * D + col] = val;
                }
            }
        }
    }
}

static inline size_t align_up(size_t v, size_t a) { return (v + a - 1) & ~(a - 1); }

extern "C" void kernel_launch(void* const* d_in, const int* in_sizes, int n_in,
                              void* d_out, int out_size, void* d_ws, size_t ws_size,
                              hipStream_t stream) {
    const float* x   = (const float*)d_in[0];
    const void*  ei  = d_in[1];
    const float* Wr1 = (const float*)d_in[2];
    const float* Wl1 = (const float*)d_in[3];
    const float* b1  = (const float*)d_in[4];
    const float* Wr2 = (const float*)d_in[5];
    const float* Wl2 = (const float*)d_in[6];
    const float* b2  = (const float*)d_in[7];
    float* out = (float*)d_out;

    const int n_nodes = in_sizes[0] / D;
    const int n_edges = in_sizes[1] / 2;

    const int nb1   = (n_nodes + BKT_W - 1) / BKT_W;        // 1563 coarse buckets
    const int nblk1 = (n_edges + EB1 - 1) / EB1;            // 391 pass-1 blocks
    const int L     = nb1 * nblk1;                          // 611k scan elements
    const int npass = (nb1 + WIN - 1) / WIN;                // 4 scatter windows
    const int nbL   = (L + 1023) / 1024;                    // 597 scan blocks

    // ws layout (~58 MB; proven available rounds 2-5)
    char* ws = (char*)d_ws;
    size_t off_flag = 0;
    size_t off_rs   = 256;                                   // row_end: n ints
    size_t off_bs   = align_up(off_rs + 4 * (size_t)(n_nodes + 1), 256);
    size_t off_ssrc = align_up(off_bs + 4 * 1024, 256);      // sorted: n_edges u32
    size_t off_wt   = align_up(off_ssrc + 4 * (size_t)n_edges, 256);
    size_t off_xb   = align_up(off_wt + 2 * (size_t)D * KTOT, 256);
    size_t off_ab   = align_up(off_xb + 2 * (size_t)n_nodes * D, 256);

    int* flag            = (int*)(ws + off_flag);
    int* row_end         = (int*)(ws + off_rs);
    int* blockSums       = (int*)(ws + off_bs);
    unsigned int* sorted = (unsigned int*)(ws + off_ssrc);
    unsigned short* Wt   = (unsigned short*)(ws + off_wt);
    unsigned short* Xb   = (unsigned short*)(ws + off_xb);
    unsigned short* Ab   = (unsigned short*)(ws + off_ab);
    // pk/bkt alias Xb (dead until cvt); C/Cs alias Ab (dead until agg L1)
    unsigned int*   pk  = (unsigned int*)(ws + off_xb);
    unsigned short* bkt = (unsigned short*)(pk + n_edges);
    int* C  = (int*)(ws + off_ab);
    int* Cs = C + L;

    const int edge_blocks = (n_edges + 255) / 256;
    const int gemm_blocks = (n_nodes + GM - 1) / GM;
    const int agg_blocks  = (n_nodes + 3) / 4;
    const long long nfeat = (long long)n_nodes * D;

    detect_kernel<<<1, 1, 0, stream>>>((const unsigned int*)ei, flag);

    // ---- CSR build: two-level counting sort, zero global atomics ----
    pack2_kernel<<<edge_blocks, 256, 0, stream>>>(ei, flag, pk, bkt, n_edges);
    s1_count_kernel<<<nblk1, 256, 0, stream>>>(bkt, n_edges, nb1, C);
    scanA_kernel<<<nbL, 1024, 0, stream>>>(C, Cs, blockSums, L, nb1, nblk1);
    scan2_kernel<<<1, 1024, 0, stream>>>(blockSums, nbL);
    scan3_kernel<<<nbL, 1024, 0, stream>>>(Cs, blockSums, L);
    for (int p = 0; p < npass; ++p) {
        s1_scatter_kernel<<<nblk1, 256, 0, stream>>>(
            bkt, pk, Cs, sorted, n_edges, nb1, nblk1, p * WIN);
    }
    bucket_sort_kernel<<<nb1, 256, 0, stream>>>(
        sorted, Cs, n_edges, n_nodes, nb1, nblk1, row_end);
    // sorted now holds src grouped by dst; row_end[i] = CSR end of node i

    // ---- casts (cvt overwrites pk/bkt — dead now) ----
    cvt_kernel<<<(int)((nfeat / 8 + 255) / 256), 256, 0, stream>>>(x, Xb, nfeat);
    wt_kernel<<<D, KTOT, 0, stream>>>(Wr1, Wl1, Wt);

    // ---- layer 1 (agg output overwrites C/Cs — dead now) ----
    agg_kernel<<<agg_blocks, 256, 0, stream>>>(Xb, (const int*)sorted, row_end, Ab, n_nodes);
    gemm_kernel<1><<<gemm_blocks, 512, 0, stream>>>(Xb, Ab, Wt, b1, Ab, n_nodes);

    // ---- layer 2 ----
    wt_kernel<<<D, KTOT, 0, stream>>>(Wr2, Wl2, Wt);
    agg_kernel<<<agg_blocks, 256, 0, stream>>>(Ab, (const int*)sorted, row_end, Xb, n_nodes);
    gemm_kernel<0><<<gemm_blocks, 512, 0, stream>>>(Ab, Xb, Wt, b2, out, n_nodes);
}

// Round 7
// 260.550 us; speedup vs baseline: 1.7843x; 1.0348x over previous
//
#include <hip/hip_runtime.h>

#define D 128
#define KTOT 256
#define GM 128
#define LPAD 8
#define LSTR (KTOT + LPAD)   // 264

#define EB1   8192    // edges per pass-1 block
#define BKT_W 64      // nodes per coarse bucket
#define WIN   1024    // buckets per scatter window (LDS cursor array, 4 KB)
#define EMAX  8192    // max edges per bucket handled in LDS (mean 1024)
#define HB1MAX 2048   // max coarse buckets (supports n_nodes <= 131072)

typedef __attribute__((ext_vector_type(8))) short bf16x8;
typedef __attribute__((ext_vector_type(4))) float f32x4;

__device__ __forceinline__ unsigned short f2b(float f) {
    unsigned int u = __float_as_uint(f);
    u += 0x7fffu + ((u >> 16) & 1u);   // RNE (inputs are finite)
    return (unsigned short)(u >> 16);
}
__device__ __forceinline__ float blo(unsigned int u) { return __uint_as_float(u << 16); }
__device__ __forceinline__ float bhi(unsigned int u) { return __uint_as_float(u & 0xffff0000u); }

// ---------------------------------------------------------------------------
// Pack: pk = (src<<6)|(dst&63), bkt = dst>>6. int64-vs-int32 layout detected
// inline per wave (odd u32 words of first 128 entries all zero => int64).
// ---------------------------------------------------------------------------
__global__ __launch_bounds__(256) void pack2_kernel(
    const void* __restrict__ ei, unsigned int* __restrict__ pk,
    unsigned short* __restrict__ bkt, int n_edges)
{
    const unsigned int* eiu = (const unsigned int*)ei;
    const int l = threadIdx.x & 63;
    unsigned int w0 = eiu[2 * l + 1];
    unsigned int w1 = eiu[2 * (l + 64) + 1];
    const int is64 = __all((w0 | w1) == 0u);

    int e = blockIdx.x * 256 + threadIdx.x;
    if (e >= n_edges) return;
    int s, d;
    if (is64) {
        const long long* p = (const long long*)ei;
        s = (int)p[e]; d = (int)p[n_edges + e];
    } else {
        const int* p = (const int*)ei;
        s = p[e]; d = p[n_edges + e];
    }
    pk[e]  = ((unsigned int)s << 6) | (unsigned int)(d & (BKT_W - 1));
    bkt[e] = (unsigned short)(d >> 6);
}

// ---------------------------------------------------------------------------
// Pass-1 count: per-block LDS histogram over coarse buckets; contiguous write
// of C[blk][bucket]. LDS atomics only.
// ---------------------------------------------------------------------------
__global__ __launch_bounds__(256) void s1_count_kernel(
    const unsigned short* __restrict__ bkt, int n_edges, int nb1,
    int* __restrict__ C)
{
    __shared__ int h[HB1MAX];
    for (int i = threadIdx.x; i < nb1; i += 256) h[i] = 0;
    __syncthreads();
    const int e0 = blockIdx.x * EB1;
    const int e1 = min(e0 + EB1, n_edges);
    for (int e = e0 + threadIdx.x; e < e1; e += 256)
        atomicAdd(&h[bkt[e]], 1);
    __syncthreads();
    int* out = C + (long long)blockIdx.x * nb1;
    for (int i = threadIdx.x; i < nb1; i += 256) out[i] = h[i];
}

// ---------------------------------------------------------------------------
// Flat exclusive scan of C in bucket-major order (gather-transpose)
// ---------------------------------------------------------------------------
__global__ __launch_bounds__(1024) void scanA_kernel(
    const int* __restrict__ C, int* __restrict__ Cs,
    int* __restrict__ blockSums, int L, int nb1, int nblk1)
{
    __shared__ int sm[1024];
    const int tid = threadIdx.x;
    const int i = blockIdx.x * 1024 + tid;
    int v = 0;
    if (i < L) {
        int b = i / nblk1, k = i - b * nblk1;
        v = C[(long long)k * nb1 + b];
    }
    int val = v;
    sm[tid] = val;
    __syncthreads();
    for (int off = 1; off < 1024; off <<= 1) {
        int t = (tid >= off) ? sm[tid - off] : 0;
        __syncthreads();
        val += t;
        sm[tid] = val;
        __syncthreads();
    }
    if (i < L) Cs[i] = val - v;
    if (tid == 1023) blockSums[blockIdx.x] = val;
}

__global__ __launch_bounds__(1024) void scan2_kernel(int* __restrict__ bs, int nb)
{
    __shared__ int sm[1024];
    int t = threadIdx.x;
    int v = (t < nb) ? bs[t] : 0;
    int val = v;
    sm[t] = val;
    __syncthreads();
    for (int off = 1; off < 1024; off <<= 1) {
        int u = (t >= off) ? sm[t - off] : 0;
        __syncthreads();
        val += u;
        sm[t] = val;
        __syncthreads();
    }
    if (t < nb) bs[t] = val - v;
}

__global__ __launch_bounds__(1024) void scan3_kernel(
    int* __restrict__ arr, const int* __restrict__ blockSums, int n)
{
    const int i = blockIdx.x * 1024 + threadIdx.x;
    if (i >= n) return;
    arr[i] += blockSums[blockIdx.x];
}

// ---------------------------------------------------------------------------
// Pass-1 scatter (windowed): cursors in LDS, seeded from Cs. Writes confined
// to a ~3.2 MB window. Zero global atomics.
// ---------------------------------------------------------------------------
__global__ __launch_bounds__(256) void s1_scatter_kernel(
    const unsigned short* __restrict__ bkt, const unsigned int* __restrict__ pk,
    const int* __restrict__ Cs, unsigned int* __restrict__ sorted,
    int n_edges, int nb1, int nblk1, int lo)
{
    __shared__ int cur[WIN];
    const int hi = min(lo + WIN, nb1);
    for (int t = threadIdx.x; t < hi - lo; t += 256)
        cur[t] = Cs[(long long)(lo + t) * nblk1 + blockIdx.x];
    __syncthreads();
    const int e0 = blockIdx.x * EB1;
    const int e1 = min(e0 + EB1, n_edges);
    for (int e = e0 + threadIdx.x; e < e1; e += 256) {
        int b = bkt[e];
        if (b >= lo && b < hi) {
            int pos = atomicAdd(&cur[b - lo], 1);   // LDS atomic
            sorted[pos] = pk[e];
        }
    }
}

// ---------------------------------------------------------------------------
// Pass-2: one block per coarse bucket. LDS 64-bin counting sort by exact dst,
// writes row_end[node] and rewrites sorted[] (pk -> src) in place.
// ---------------------------------------------------------------------------
__global__ __launch_bounds__(256) void bucket_sort_kernel(
    unsigned int* __restrict__ sorted, const int* __restrict__ Cs,
    int n_edges, int n_nodes, int nb1, int nblk1, int* __restrict__ row_end)
{
    __shared__ unsigned int lpk[EMAX];
    __shared__ int h64[BKT_W], excl[BKT_W + 1], cur[BKT_W];
    const int b = blockIdx.x;
    const int t = threadIdx.x;
    const int base = Cs[(long long)b * nblk1];
    const int nextb = (b + 1 < nb1) ? Cs[(long long)(b + 1) * nblk1] : n_edges;
    const int cnt = min(nextb - base, EMAX);

    if (t < BKT_W) h64[t] = 0;
    for (int i = t; i < cnt; i += 256) lpk[i] = sorted[base + i];
    __syncthreads();
    for (int i = t; i < cnt; i += 256) atomicAdd(&h64[lpk[i] & (BKT_W - 1)], 1);
    __syncthreads();
    if (t == 0) {
        int run = 0;
        #pragma unroll
        for (int i = 0; i < BKT_W; ++i) { excl[i] = run; run += h64[i]; }
        excl[BKT_W] = run;
    }
    __syncthreads();
    const int node0 = b * BKT_W;
    const int bins = min(BKT_W, n_nodes - node0);
    if (t < bins) row_end[node0 + t] = base + excl[t + 1];
    if (t < BKT_W) cur[t] = excl[t];
    __syncthreads();
    for (int i = t; i < cnt; i += 256) {
        unsigned int p = lpk[i];
        int pos = atomicAdd(&cur[p & (BKT_W - 1)], 1);   // LDS atomic
        sorted[base + pos] = p >> 6;                     // src
    }
}

// ---------------------------------------------------------------------------
// Fused prep: blocks [0,nbcvt) do f32->bf16 convert of x; blocks
// [nbcvt,nbcvt+128) build Wt1; [nbcvt+128,nbcvt+256) build Wt2.
// Wt[c][k] = (k<128 ? Wr[k][c] : Wl[k-128][c]) as bf16  — [128][256]
// ---------------------------------------------------------------------------
__global__ __launch_bounds__(256) void prep_kernel(
    const float* __restrict__ x, unsigned short* __restrict__ Xb,
    long long nelem, int nbcvt,
    const float* __restrict__ Wr1, const float* __restrict__ Wl1,
    unsigned short* __restrict__ Wt1,
    const float* __restrict__ Wr2, const float* __restrict__ Wl2,
    unsigned short* __restrict__ Wt2)
{
    const int b = blockIdx.x;
    if (b < nbcvt) {
        long long i = ((long long)b * 256 + threadIdx.x) * 8;
        if (i >= nelem) return;
        float4 a = *(const float4*)(x + i);
        float4 c = *(const float4*)(x + i + 4);
        bf16x8 v;
        v[0] = (short)f2b(a.x); v[1] = (short)f2b(a.y);
        v[2] = (short)f2b(a.z); v[3] = (short)f2b(a.w);
        v[4] = (short)f2b(c.x); v[5] = (short)f2b(c.y);
        v[6] = (short)f2b(c.z); v[7] = (short)f2b(c.w);
        *(bf16x8*)(Xb + i) = v;
    } else {
        const int cb = b - nbcvt;                 // 0..255
        const float* Wr = (cb < 128) ? Wr1 : Wr2;
        const float* Wl = (cb < 128) ? Wl1 : Wl2;
        unsigned short* Wt = (cb < 128) ? Wt1 : Wt2;
        const int c = cb & 127;
        const int k = threadIdx.x;
        float v = (k < 128) ? Wr[k * D + c] : Wl[(k - 128) * D + c];
        Wt[c * KTOT + k] = f2b(v);
    }
}

// ---------------------------------------------------------------------------
// CSR gather aggregation: wave per node, 16 lanes x uint4 per row,
// 4 slots x 4-deep unroll => 16 independent gathers in flight per wave.
// ---------------------------------------------------------------------------
#define ACC8(u) { a0 += blo(u.x); a1 += bhi(u.x); a2 += blo(u.y); a3 += bhi(u.y); \
                  a4 += blo(u.z); a5 += bhi(u.z); a6 += blo(u.w); a7 += bhi(u.w); }

__global__ __launch_bounds__(256) void agg_kernel(
    const unsigned short* __restrict__ src, const int* __restrict__ sorted_src,
    const int* __restrict__ row_end, unsigned short* __restrict__ dst, int n)
{
    const int node = blockIdx.x * 4 + (threadIdx.x >> 6);
    if (node >= n) return;
    const int lane = threadIdx.x & 63;
    const int j = lane >> 4;
    const int c = (lane & 15) * 8;
    const int beg = node ? row_end[node - 1] : 0;
    const int end = row_end[node];

    float a0 = 0.f, a1 = 0.f, a2 = 0.f, a3 = 0.f,
          a4 = 0.f, a5 = 0.f, a6 = 0.f, a7 = 0.f;

    int i = beg + j;
    for (; i + 12 < end; i += 16) {
        int s0 = sorted_src[i];
        int s1 = sorted_src[i + 4];
        int s2 = sorted_src[i + 8];
        int s3 = sorted_src[i + 12];
        uint4 u0 = *(const uint4*)(src + (long long)s0 * D + c);
        uint4 u1 = *(const uint4*)(src + (long long)s1 * D + c);
        uint4 u2 = *(const uint4*)(src + (long long)s2 * D + c);
        uint4 u3 = *(const uint4*)(src + (long long)s3 * D + c);
        ACC8(u0); ACC8(u1); ACC8(u2); ACC8(u3);
    }
    for (; i < end; i += 4) {
        int s0 = sorted_src[i];
        uint4 u0 = *(const uint4*)(src + (long long)s0 * D + c);
        ACC8(u0);
    }

    a0 += __shfl_xor(a0, 16); a1 += __shfl_xor(a1, 16);
    a2 += __shfl_xor(a2, 16); a3 += __shfl_xor(a3, 16);
    a4 += __shfl_xor(a4, 16); a5 += __shfl_xor(a5, 16);
    a6 += __shfl_xor(a6, 16); a7 += __shfl_xor(a7, 16);
    a0 += __shfl_xor(a0, 32); a1 += __shfl_xor(a1, 32);
    a2 += __shfl_xor(a2, 32); a3 += __shfl_xor(a3, 32);
    a4 += __shfl_xor(a4, 32); a5 += __shfl_xor(a5, 32);
    a6 += __shfl_xor(a6, 32); a7 += __shfl_xor(a7, 32);

    if (j == 0) {
        uint4 p;
        p.x = (unsigned int)f2b(a0) | ((unsigned int)f2b(a1) << 16);
        p.y = (unsigned int)f2b(a2) | ((unsigned int)f2b(a3) << 16);
        p.z = (unsigned int)f2b(a4) | ((unsigned int)f2b(a5) << 16);
        p.w = (unsigned int)f2b(a6) | ((unsigned int)f2b(a7) << 16);
        *(uint4*)(dst + (long long)node * D + c) = p;
    }
}

// ---------------------------------------------------------------------------
// MFMA GEMM: out = relu([X|A] @ Wt^T + b). A-fragments direct from global
// (one consumer wave per row -> LDS staging has no reuse). Wt LDS-staged.
// outp may alias Aop (waves read only their own 16-row span before writing).
// ---------------------------------------------------------------------------
template <int OUT_BF16>
__global__ __launch_bounds__(512) void gemm_kernel(
    const unsigned short* __restrict__ Xop, const unsigned short* __restrict__ Aop,
    const unsigned short* __restrict__ Wt, const float* __restrict__ bias,
    void* outp, int n)
{
    __shared__ short sW[D][LSTR];
    const int tid = threadIdx.x;
    const int r0 = blockIdx.x * GM;

    for (int i = 0; i < 8; ++i) {
        int idx = tid + i * 512;
        int r = idx >> 5, c8 = idx & 31;
        bf16x8 w = *(const bf16x8*)(Wt + r * KTOT + c8 * 8);
        *(bf16x8*)&sW[r][c8 * 8] = w;
    }
    __syncthreads();

    const int w    = tid >> 6;
    const int lane = tid & 63;
    const int lr   = lane & 15;
    const int lk   = (lane >> 4) * 8;
    const int row  = r0 + w * 16 + lr;
    const bool rok = (row < n);

    f32x4 acc[8];
    #pragma unroll
    for (int ct = 0; ct < 8; ++ct) acc[ct] = (f32x4){0.f, 0.f, 0.f, 0.f};

    #pragma unroll
    for (int ks = 0; ks < 8; ++ks) {
        bf16x8 a = {};
        if (rok) {
            const unsigned short* base = (ks < 4) ? Xop : Aop;
            a = *(const bf16x8*)(base + (long long)row * D + (ks & 3) * 32 + lk);
        }
        #pragma unroll
        for (int ct = 0; ct < 8; ++ct) {
            bf16x8 bf = *(const bf16x8*)&sW[ct * 16 + lr][ks * 32 + lk];
            acc[ct] = __builtin_amdgcn_mfma_f32_16x16x32_bf16(a, bf, acc[ct], 0, 0, 0);
        }
    }

    // C/D: col = lane&15, row = (lane>>4)*4 + j
    const int rbase = r0 + w * 16 + (lane >> 4) * 4;
    #pragma unroll
    for (int ct = 0; ct < 8; ++ct) {
        const int col = ct * 16 + lr;
        const float bv = bias[col];
        #pragma unroll
        for (int j = 0; j < 4; ++j) {
            int orow = rbase + j;
            if (orow < n) {
                float val = fmaxf(acc[ct][j] + bv, 0.f);
                if (OUT_BF16) {
                    ((unsigned short*)outp)[(long long)orow * D + col] = f2b(val);
                } else {
                    ((float*)outp)[(long long)orow * D + col] = val;
                }
            }
        }
    }
}

static inline size_t align_up(size_t v, size_t a) { return (v + a - 1) & ~(a - 1); }

extern "C" void kernel_launch(void* const* d_in, const int* in_sizes, int n_in,
                              void* d_out, int out_size, void* d_ws, size_t ws_size,
                              hipStream_t stream) {
    const float* x   = (const float*)d_in[0];
    const void*  ei  = d_in[1];
    const float* Wr1 = (const float*)d_in[2];
    const float* Wl1 = (const float*)d_in[3];
    const float* b1  = (const float*)d_in[4];
    const float* Wr2 = (const float*)d_in[5];
    const float* Wl2 = (const float*)d_in[6];
    const float* b2  = (const float*)d_in[7];
    float* out = (float*)d_out;

    const int n_nodes = in_sizes[0] / D;
    const int n_edges = in_sizes[1] / 2;

    const int nb1   = (n_nodes + BKT_W - 1) / BKT_W;        // 1563 coarse buckets
    const int nblk1 = (n_edges + EB1 - 1) / EB1;            // 196 pass-1 blocks
    const int L     = nb1 * nblk1;                          // ~306k scan elements
    const int npass = (nb1 + WIN - 1) / WIN;                // 2 scatter windows
    const int nbL   = (L + 1023) / 1024;                    // ~300 scan blocks

    // ws layout (~58 MB; proven available rounds 2-6)
    char* ws = (char*)d_ws;
    size_t off_rs   = 0;                                     // row_end: n ints
    size_t off_bs   = align_up(off_rs + 4 * (size_t)(n_nodes + 1), 256);
    size_t off_ssrc = align_up(off_bs + 4 * 1024, 256);      // sorted: n_edges u32
    size_t off_wt1  = align_up(off_ssrc + 4 * (size_t)n_edges, 256);
    size_t off_wt2  = align_up(off_wt1 + 2 * (size_t)D * KTOT, 256);
    size_t off_xb   = align_up(off_wt2 + 2 * (size_t)D * KTOT, 256);
    size_t off_ab   = align_up(off_xb + 2 * (size_t)n_nodes * D, 256);

    int* row_end         = (int*)(ws + off_rs);
    int* blockSums       = (int*)(ws + off_bs);
    unsigned int* sorted = (unsigned int*)(ws + off_ssrc);
    unsigned short* Wt1  = (unsigned short*)(ws + off_wt1);
    unsigned short* Wt2  = (unsigned short*)(ws + off_wt2);
    unsigned short* Xb   = (unsigned short*)(ws + off_xb);
    unsigned short* Ab   = (unsigned short*)(ws + off_ab);
    // pk/bkt alias Xb (dead until prep); C/Cs alias Ab (dead until agg L1)
    unsigned int*   pk  = (unsigned int*)(ws + off_xb);
    unsigned short* bkt = (unsigned short*)(pk + n_edges);
    int* C  = (int*)(ws + off_ab);
    int* Cs = C + L;

    const int edge_blocks = (n_edges + 255) / 256;
    const int gemm_blocks = (n_nodes + GM - 1) / GM;
    const int agg_blocks  = (n_nodes + 3) / 4;
    const long long nfeat = (long long)n_nodes * D;
    const int nbcvt = (int)((nfeat / 8 + 255) / 256);

    // ---- CSR build: two-level counting sort, zero global atomics ----
    pack2_kernel<<<edge_blocks, 256, 0, stream>>>(ei, pk, bkt, n_edges);
    s1_count_kernel<<<nblk1, 256, 0, stream>>>(bkt, n_edges, nb1, C);
    scanA_kernel<<<nbL, 1024, 0, stream>>>(C, Cs, blockSums, L, nb1, nblk1);
    scan2_kernel<<<1, 1024, 0, stream>>>(blockSums, nbL);
    scan3_kernel<<<nbL, 1024, 0, stream>>>(Cs, blockSums, L);
    for (int p = 0; p < npass; ++p) {
        s1_scatter_kernel<<<nblk1, 256, 0, stream>>>(
            bkt, pk, Cs, sorted, n_edges, nb1, nblk1, p * WIN);
    }

    // ---- prep: cvt x->bf16 + both Wt (overwrites pk/bkt — dead now) ----
    prep_kernel<<<nbcvt + 256, 256, 0, stream>>>(
        x, Xb, nfeat, nbcvt, Wr1, Wl1, Wt1, Wr2, Wl2, Wt2);

    bucket_sort_kernel<<<nb1, 256, 0, stream>>>(
        sorted, Cs, n_edges, n_nodes, nb1, nblk1, row_end);
    // sorted now holds src grouped by dst; row_end[i] = CSR end of node i

    // ---- layer 1 (agg output overwrites C/Cs — dead now) ----
    agg_kernel<<<agg_blocks, 256, 0, stream>>>(Xb, (const int*)sorted, row_end, Ab, n_nodes);
    gemm_kernel<1><<<gemm_blocks, 512, 0, stream>>>(Xb, Ab, Wt1, b1, Ab, n_nodes);

    // ---- layer 2 ----
    agg_kernel<<<agg_blocks, 256, 0, stream>>>(Ab, (const int*)sorted, row_end, Xb, n_nodes);
    gemm_kernel<0><<<gemm_blocks, 512, 0, stream>>>(Ab, Xb, Wt2, b2, out, n_nodes);
}